// Round 1
// 479.764 us; speedup vs baseline: 1.0079x; 1.0079x over previous
//
#include <hip/hip_runtime.h>

#define NN 4096
#define HH 32
#define DD 128
#define MM 16
#define PP 8192

__device__ __forceinline__ float4 ld4(const float* p) { return *(const float4*)(p); }
__device__ __forceinline__ float dot4f(float4 a, float4 b) {
  return a.x * b.x + a.y * b.y + a.z * b.z + a.w * b.w;
}

// ---------------------------------------------------------------- K1: RMS inv
__global__ void k1_rms(const float* __restrict__ X, float* __restrict__ inv) {
  const int m = blockIdx.x;
  const int tid = threadIdx.x;
  float s = 0.f;
#pragma unroll
  for (int i = 0; i < 16; ++i) {
    float v = X[(size_t)m * NN + i * 256 + tid];
    s += v * v;
  }
#pragma unroll
  for (int off = 1; off < 64; off <<= 1) s += __shfl_xor(s, off, 64);
  __shared__ float red[4];
  if ((tid & 63) == 0) red[tid >> 6] = s;
  __syncthreads();
  if (tid == 0) {
    float t = red[0] + red[1] + red[2] + red[3];
    inv[m] = rsqrtf(t * (1.0f / (float)NN));
  }
}

// ------------------------------------------------- K2: QKV quarter partials
// grid 1536 = 3 mats x 4 k-quarters x 128 row-blocks(32 rows). block 256.
// W staged global->regs->LDS double-buffered (4-row x 1024-k tiles, 16 KB);
// staging loads fully coalesced. X in registers. lane=(m4,g16): 4 m x 16 k.
__global__ __launch_bounds__(256, 3) void k2_qkv(
    const float* __restrict__ X, const float* __restrict__ Wq,
    const float* __restrict__ Wk, const float* __restrict__ Wv,
    float* __restrict__ c_part) {
  __shared__ float wt[2][4][1024];     // 32 KB double buffer
  __shared__ float lds_c[4][32][17];   // wave partial combine
  const int b = blockIdx.x;
  const int mat = b >> 9;
  const int qt = (b >> 7) & 3;
  const int rb = b & 127;              // rows rb*32 .. +31
  const float* W = (mat == 0) ? Wq : (mat == 1) ? Wk : Wv;
  const int tid = threadIdx.x;
  const int wave = tid >> 6;
  const int lane = tid & 63;
  const int m4 = lane & 3;
  const int g = lane >> 2;
  const int kwin = wave * 256 + g * 16;       // within the 1024-k quarter
  const int kbase = qt * 1024 + kwin;         // global k offset

  float4 xr[4][4];  // X[m = mi*4+m4][16 k slice]
#pragma unroll
  for (int mi = 0; mi < 4; ++mi) {
    const float* xp = X + (size_t)(mi * 4 + m4) * NN + kbase;
#pragma unroll
    for (int j = 0; j < 4; ++j) xr[mi][j] = ld4(xp + j * 4);
  }

  // staging: tile = 4 rows x 1024 floats = 1024 float4; 4 per thread
  const float* Wbase = W + (size_t)(rb * 32) * NN + qt * 1024;
  float4 rw[4];
#pragma unroll
  for (int i = 0; i < 4; ++i) {
    const int id = tid + i * 256;
    rw[i] = *((const float4*)(Wbase + (size_t)(id >> 8) * NN) + (id & 255));
  }

  for (int tt = 0; tt < 8; ++tt) {
    __syncthreads();
#pragma unroll
    for (int i = 0; i < 4; ++i)
      ((float4*)wt[tt & 1])[tid + i * 256] = rw[i];
    __syncthreads();
    if (tt < 7) {
      const float* Wn = Wbase + (size_t)((tt + 1) * 4) * NN;
#pragma unroll
      for (int i = 0; i < 4; ++i) {
        const int id = tid + i * 256;
        rw[i] = *((const float4*)(Wn + (size_t)(id >> 8) * NN) + (id & 255));
      }
    }
    // compute this tile's 4 rows
    float acc[4][4];
#pragma unroll
    for (int r = 0; r < 4; ++r)
#pragma unroll
      for (int mi = 0; mi < 4; ++mi) acc[r][mi] = 0.f;
#pragma unroll
    for (int r = 0; r < 4; ++r) {
      const float* wp = wt[tt & 1][r] + kwin;
      float4 w0 = ld4(wp), w1 = ld4(wp + 4), w2 = ld4(wp + 8), w3 = ld4(wp + 12);
#pragma unroll
      for (int mi = 0; mi < 4; ++mi)
        acc[r][mi] += dot4f(xr[mi][0], w0) + dot4f(xr[mi][1], w1) +
                      dot4f(xr[mi][2], w2) + dot4f(xr[mi][3], w3);
    }
#pragma unroll
    for (int off = 4; off < 64; off <<= 1)
#pragma unroll
      for (int r = 0; r < 4; ++r)
#pragma unroll
        for (int mi = 0; mi < 4; ++mi)
          acc[r][mi] += __shfl_xor(acc[r][mi], off, 64);
    if (g == 0) {
#pragma unroll
      for (int r = 0; r < 4; ++r)
#pragma unroll
        for (int mi = 0; mi < 4; ++mi)
          lds_c[wave][tt * 4 + r][mi * 4 + m4] = acc[r][mi];
    }
  }
  __syncthreads();
  // combine 4 waves' k-sub-slices -> quarter partial [mat*4+qt][m][4096]
#pragma unroll
  for (int i = 0; i < 2; ++i) {
    const int idx = i * 256 + tid;
    const int l = idx >> 4;   // local row 0..31
    const int m = idx & 15;
    float s = lds_c[0][l][m] + lds_c[1][l][m] + lds_c[2][l][m] + lds_c[3][l][m];
    c_part[(((size_t)(mat * 4 + qt) * 16 + m) << 12) + (rb * 32 + l)] = s;
  }
}

// --------------------------------------- K2b: combine quarters, scale by inv
// qkv[mat][m][j=h*128+d] = inv[m] * sum_qt c_part[mat][qt][m][j]
__global__ void k2b_combine(const float* __restrict__ c_part,
                            const float* __restrict__ inv,
                            float* __restrict__ qkv) {
  const int t = blockIdx.x * 256 + threadIdx.x;  // 0..196607
  const int mat = t >> 16;
  const int r = t & 65535;
  const int m = r >> 12;
  const int j = r & 4095;
  float s = 0.f;
#pragma unroll
  for (int qt = 0; qt < 4; ++qt)
    s += c_part[(((size_t)(mat * 4 + qt) * 16 + m) << 12) + j];
  qkv[(((size_t)(mat * 16 + m)) << 12) + j] = s * inv[m];
}

// ------------------------------------------------- K3: attention partials
// grid 1024 = 32 h x 32 seg (256 rows each; 4 blocks/CU, 16 waves/CU).
// NO LDS staging: each p-row is consumed by exactly one wave, so LDS gave
// zero cross-wave reuse and cost 80KB (2 blk/CU cap) + 2 barriers/tile +
// 4-way bank conflicts. Waves stream K/V rows global->regs directly, fully
// independent (no barrier in main loop). lane=(m8,g8): 2 m x 16 d;
// 3-stage shuffle reduce per row. Block-level LDS combine in epilogue
// halves o_part traffic vs per-wave partials.
// Block with seg==h also handles the 16 appended rows from qkv.
__global__ __launch_bounds__(256, 4) void k3_attn(
    const float* __restrict__ cK, const float* __restrict__ cV,
    const float* __restrict__ qkv, float* __restrict__ o_part,
    float* __restrict__ den_part) {
  __shared__ float sO[4][16][132];   // +4 pad: conflict-light epilogue
  __shared__ float sD[4][16];
  const int b = blockIdx.x;
  const int h = b >> 5;
  const int seg = b & 31;
  const int tid = threadIdx.x;
  const int wave = tid >> 6;
  const int lane = tid & 63;
  const int m8 = lane & 7;
  const int g = lane >> 3;
  const int d0 = g * 16;

  // q fragments for m = m8 and m8+8
  float4 q0[4], q1[4];
  {
    const float* qa = qkv + (size_t)m8 * NN + h * DD + d0;
    const float* qb = qkv + (size_t)(m8 + 8) * NN + h * DD + d0;
#pragma unroll
    for (int j = 0; j < 4; ++j) { q0[j] = ld4(qa + j * 4); q1[j] = ld4(qb + j * 4); }
  }
  float o0[16], o1[16];
#pragma unroll
  for (int j = 0; j < 16; ++j) { o0[j] = 0.f; o1[j] = 0.f; }
  float den0 = 0.f, den1 = 0.f;

  const size_t rowbase = (size_t)h * PP + (size_t)seg * 256 + wave * 64;
  const float* kp = cK + rowbase * DD + d0;
  const float* vp = cV + rowbase * DD + d0;

  for (int i = 0; i < 64; ++i) {
    float4 k0 = ld4(kp), k1 = ld4(kp + 4), k2 = ld4(kp + 8), k3 = ld4(kp + 12);
    float4 v0 = ld4(vp), v1 = ld4(vp + 4), v2 = ld4(vp + 8), v3 = ld4(vp + 12);
    kp += DD; vp += DD;
    float c0 = dot4f(q0[0], k0) + dot4f(q0[1], k1) + dot4f(q0[2], k2) + dot4f(q0[3], k3);
    float c1 = dot4f(q1[0], k0) + dot4f(q1[1], k1) + dot4f(q1[2], k2) + dot4f(q1[3], k3);
#pragma unroll
    for (int off = 8; off < 64; off <<= 1) {
      c0 += __shfl_xor(c0, off, 64);
      c1 += __shfl_xor(c1, off, 64);
    }
    float e0 = __expf(c0), e1 = __expf(c1);
    den0 += e0; den1 += e1;
    o0[0] += e0 * v0.x;  o0[1] += e0 * v0.y;  o0[2] += e0 * v0.z;  o0[3] += e0 * v0.w;
    o0[4] += e0 * v1.x;  o0[5] += e0 * v1.y;  o0[6] += e0 * v1.z;  o0[7] += e0 * v1.w;
    o0[8] += e0 * v2.x;  o0[9] += e0 * v2.y;  o0[10] += e0 * v2.z; o0[11] += e0 * v2.w;
    o0[12] += e0 * v3.x; o0[13] += e0 * v3.y; o0[14] += e0 * v3.z; o0[15] += e0 * v3.w;
    o1[0] += e1 * v0.x;  o1[1] += e1 * v0.y;  o1[2] += e1 * v0.z;  o1[3] += e1 * v0.w;
    o1[4] += e1 * v1.x;  o1[5] += e1 * v1.y;  o1[6] += e1 * v1.z;  o1[7] += e1 * v1.w;
    o1[8] += e1 * v2.x;  o1[9] += e1 * v2.y;  o1[10] += e1 * v2.z; o1[11] += e1 * v2.w;
    o1[12] += e1 * v3.x; o1[13] += e1 * v3.y; o1[14] += e1 * v3.z; o1[15] += e1 * v3.w;
  }

  // appended 16 rows (k = qkv mat1, v = qkv mat2): block (h, seg==h) only,
  // 4 rows per wave, read straight from qkv (tiny, L2-resident).
  if (seg == h) {
#pragma unroll
    for (int pi = 0; pi < 4; ++pi) {
      const int p = wave * 4 + pi;
      const float* kq = qkv + (size_t)(16 + p) * NN + h * DD + d0;
      const float* vq = qkv + (size_t)(32 + p) * NN + h * DD + d0;
      float4 k0 = ld4(kq), k1 = ld4(kq + 4), k2 = ld4(kq + 8), k3 = ld4(kq + 12);
      float c0 = dot4f(q0[0], k0) + dot4f(q0[1], k1) + dot4f(q0[2], k2) + dot4f(q0[3], k3);
      float c1 = dot4f(q1[0], k0) + dot4f(q1[1], k1) + dot4f(q1[2], k2) + dot4f(q1[3], k3);
#pragma unroll
      for (int off = 8; off < 64; off <<= 1) {
        c0 += __shfl_xor(c0, off, 64);
        c1 += __shfl_xor(c1, off, 64);
      }
      float e0 = __expf(c0), e1 = __expf(c1);
      den0 += e0; den1 += e1;
      float4 v0 = ld4(vq), v1 = ld4(vq + 4), v2 = ld4(vq + 8), v3 = ld4(vq + 12);
      o0[0] += e0 * v0.x;  o0[1] += e0 * v0.y;  o0[2] += e0 * v0.z;  o0[3] += e0 * v0.w;
      o0[4] += e0 * v1.x;  o0[5] += e0 * v1.y;  o0[6] += e0 * v1.z;  o0[7] += e0 * v1.w;
      o0[8] += e0 * v2.x;  o0[9] += e0 * v2.y;  o0[10] += e0 * v2.z; o0[11] += e0 * v2.w;
      o0[12] += e0 * v3.x; o0[13] += e0 * v3.y; o0[14] += e0 * v3.z; o0[15] += e0 * v3.w;
      o1[0] += e1 * v0.x;  o1[1] += e1 * v0.y;  o1[2] += e1 * v0.z;  o1[3] += e1 * v0.w;
      o1[4] += e1 * v1.x;  o1[5] += e1 * v1.y;  o1[6] += e1 * v1.z;  o1[7] += e1 * v1.w;
      o1[8] += e1 * v2.x;  o1[9] += e1 * v2.y;  o1[10] += e1 * v2.z; o1[11] += e1 * v2.w;
      o1[12] += e1 * v3.x; o1[13] += e1 * v3.y; o1[14] += e1 * v3.z; o1[15] += e1 * v3.w;
    }
  }

  // block-level combine of the 4 wave partials (single barrier, LDS is free)
#pragma unroll
  for (int j = 0; j < 4; ++j) {
    *(float4*)&sO[wave][m8][d0 + j * 4] =
        make_float4(o0[j * 4], o0[j * 4 + 1], o0[j * 4 + 2], o0[j * 4 + 3]);
    *(float4*)&sO[wave][m8 + 8][d0 + j * 4] =
        make_float4(o1[j * 4], o1[j * 4 + 1], o1[j * 4 + 2], o1[j * 4 + 3]);
  }
  if (g == 0) { sD[wave][m8] = den0; sD[wave][8 + m8] = den1; }
  __syncthreads();
#pragma unroll
  for (int e = 0; e < 8; ++e) {
    const int idx = e * 256 + tid;          // 0..2047 = m*128+d
    const int m = idx >> 7;
    const int d = idx & 127;
    o_part[(size_t)b * 2048 + idx] =
        sO[0][m][d] + sO[1][m][d] + sO[2][m][d] + sO[3][m][d];
  }
  if (tid < 16)
    den_part[(size_t)b * 16 + tid] =
        sD[0][tid] + sD[1][tid] + sD[2][tid] + sD[3][tid];
}

// -------------------------------------------------------- K4: final reduce
// grid 256 = 32 h x 8 sub; sum 32 block-partials per head, divide, write out.
__global__ void k4_final(const float* __restrict__ o_part,
                         const float* __restrict__ den_part,
                         float* __restrict__ out) {
  const int b = blockIdx.x;
  const int h = b >> 3;
  const int tid = threadIdx.x;
  const int idx = (b & 7) * 256 + tid;  // 0..2047 = m*128+d
  __shared__ float dinv[16];
  if (tid < 16) {
    float s = 0.f;
    for (int j = 0; j < 32; ++j) s += den_part[(size_t)h * 512 + j * 16 + tid];
    dinv[tid] = 1.0f / s;
  }
  __syncthreads();
  float s = 0.f;
  for (int j = 0; j < 32; ++j) s += o_part[(size_t)h * 65536 + j * 2048 + idx];
  const int m = idx >> 7;
  const int d = idx & 127;
  out[(size_t)m * NN + h * DD + d] = s * dinv[m];
}

extern "C" void kernel_launch(void* const* d_in, const int* in_sizes, int n_in,
                              void* d_out, int out_size, void* d_ws, size_t ws_size,
                              hipStream_t stream) {
  (void)in_sizes; (void)n_in; (void)out_size; (void)ws_size;
  const float* X  = (const float*)d_in[0];
  const float* Wq = (const float*)d_in[1];
  const float* Wk = (const float*)d_in[2];
  const float* Wv = (const float*)d_in[3];
  const float* cK = (const float*)d_in[4];
  const float* cV = (const float*)d_in[5];
  float* out = (float*)d_out;
  float* ws = (float*)d_ws;

  float* inv      = ws;                  // 16
  float* c_part   = ws + 16;             // 3*4*16*4096 = 786432
  float* qkv      = c_part + 786432;     // 3*16*4096   = 196608
  float* o_part   = qkv + 196608;        // 1024*2048   = 2097152
  float* den_part = o_part + 2097152;    // 1024*16     = 16384
  // total ~12.4 MB

  k1_rms<<<16, 256, 0, stream>>>(X, inv);
  k2_qkv<<<1536, 256, 0, stream>>>(X, Wq, Wk, Wv, c_part);
  k2b_combine<<<768, 256, 0, stream>>>(c_part, inv, qkv);
  k3_attn<<<dim3(1024), 256, 0, stream>>>(cK, cV, qkv, o_part, den_part);
  k4_final<<<256, 256, 0, stream>>>(o_part, den_part, out);
}